// Round 10
// baseline (277.635 us; speedup 1.0000x reference)
//
#include <hip/hip_runtime.h>
#include <hip/hip_bf16.h>
#include <hip/hip_fp8.h>

typedef unsigned char u8;
typedef unsigned int u32;
typedef __attribute__((ext_vector_type(4))) int i32x4;
typedef __attribute__((ext_vector_type(8))) int i32x8;
typedef __attribute__((ext_vector_type(16))) float f32x16;

#define NB 4096
#define ND 512
#define NREPS (3*NB)
#define BM 128
#define BN 256
#define SCL 0x7F7F7F7F   // e8m0 scale bytes = 127 -> 1.0

__device__ __forceinline__ u32 pk4(float a, float b, float c, float d) {
  __hip_fp8_e4m3 qa(a), qb(b), qc(c), qd(d);
  return (u32)qa.__x | ((u32)qb.__x << 8) | ((u32)qc.__x << 16) | ((u32)qd.__x << 24);
}

// Fused prep: waves 0..2 convert ts/i1/i2 row r -> fp8 reps + fp32 norms
// (norms from ORIGINAL fp32 -> quantization error only in the cross-dot);
// i1/i2 rows pass through LDS to wave 3 (dist12 + minsq init).
__global__ __launch_bounds__(256) void prep_all(
    const float* __restrict__ ts, const float* __restrict__ i1,
    const float* __restrict__ i2, u8* __restrict__ reps,
    float* __restrict__ norms, float* __restrict__ dist12,
    u32* __restrict__ minsq)
{
  __shared__ float s1[ND], s2[ND];
  const int r = blockIdx.x;
  const int tid = threadIdx.x;
  const int wave = tid >> 6, lane = tid & 63;

  if (wave < 3) {
    const float* src = (wave == 0) ? ts + (size_t)r * ND
                     : (wave == 1) ? i1 + (size_t)r * ND
                     :               i2 + (size_t)r * ND;
    const float4* s4 = (const float4*)src;
    float4 a = s4[lane*2+0];
    float4 b = s4[lane*2+1];
    if (wave == 1) { ((float4*)s1)[lane*2+0] = a; ((float4*)s1)[lane*2+1] = b; }
    if (wave == 2) { ((float4*)s2)[lane*2+0] = a; ((float4*)s2)[lane*2+1] = b; }
    float ss = a.x*a.x + a.y*a.y + a.z*a.z + a.w*a.w
             + b.x*b.x + b.y*b.y + b.z*b.z + b.w*b.w;
    uint2 pk;
    pk.x = pk4(a.x, a.y, a.z, a.w);
    pk.y = pk4(b.x, b.y, b.z, b.w);
    *(uint2*)(reps + (size_t)(wave*NB + r) * ND + lane*8) = pk;
    #pragma unroll
    for (int off = 32; off; off >>= 1) ss += __shfl_down(ss, off);
    if (lane == 0) norms[wave*NB + r] = ss;
  }
  __syncthreads();
  if (wave == 3) {
    float ss = 0.f;
    #pragma unroll
    for (int i = 0; i < 2; ++i) {
      float4 a = ((float4*)s1)[lane*2+i];
      float4 b = ((float4*)s2)[lane*2+i];
      float d0 = a.x - b.x + 1e-6f, d1 = a.y - b.y + 1e-6f;
      float d2 = a.z - b.z + 1e-6f, d3 = a.w - b.w + 1e-6f;
      ss += d0*d0 + d1*d1 + d2*d2 + d3*d3;
    }
    #pragma unroll
    for (int off = 32; off; off >>= 1) ss += __shfl_down(ss, off);
    if (lane == 0) { dist12[r] = sqrtf(ss); minsq[r] = 0x7F800000u; }
  }
}

// Load a 32B f8f6f4 operand fragment straight from global (L2-resident):
// lane holds row p's 32 k-bytes; emitted as 2x global_load_dwordx4.
__device__ __forceinline__ i32x8 ld32(const u8* __restrict__ p) {
  const i32x4 lo = *(const i32x4*)p;
  const i32x4 h  = *(const i32x4*)(p + 16);
  i32x8 r;
  r[0]=lo[0]; r[1]=lo[1]; r[2]=lo[2]; r[3]=lo[3];
  r[4]=h[0];  r[5]=h[1];  r[6]=h[2];  r[7]=h[3];
  return r;
}

#define MFMA8(a,b,c) __builtin_amdgcn_mfma_scale_f32_32x32x64_f8f6f4(          \
    (a), (b), (c), 0, 0, 0, SCL, 0, SCL)

// Fused distance-GEMM (MX-fp8, scale=1.0) + per-row min + diagonal picks.
// NO LDS, NO BARRIERS: R2/R7/R9 all plateaued at 500-570 TF because the
// stage->vmcnt(0)->compute LDS round-trip serializes the L2->LDS transfer
// (~900 cy/K-step) behind every barrier. Here each wave loads its MFMA
// operands global->VGPR directly (fp8 reps = 6.3 MB, L2-resident; A-frag
// lanes l/l+32 share one 64B line). 1-deep E/O named-register prefetch
// (no runtime-indexed arrays -> no scratch), latency hidden by ~12 waves/CU.
// Block = 8 waves (2M x 4N) = 128x256 tile; wave-tile 64x64 = 2x2 frags of
// 32x32x64. Grid 32x48 M-fastest (R5 lesson: XCD swizzle quadrupled FETCH).
__global__ __launch_bounds__(512) void gemm_min(
    const u8* __restrict__ reps, const float* __restrict__ norms,
    u32* __restrict__ minsq, float* __restrict__ lpos1,
    float* __restrict__ lpos2)
{
  const int tid  = threadIdx.x;
  const int lane = tid & 63;
  const int wave = tid >> 6;          // 0..7
  const int wr = wave >> 2;           // 0..1 (M half: 64 rows)
  const int wc = wave & 3;            // 0..3 (N quarter: 64 cols)
  const int lc = lane & 31;           // row/col within 32x32 frag
  const int hi = lane >> 5;           // k-half selector

  const int rowBase = blockIdx.x * BM;   // ts rows
  const int colBase = blockIdx.y * BN;   // reps rows (output cols)

  const u8* pa0 = reps + (size_t)(rowBase + wr*64      + lc) * ND + hi*32;
  const u8* pa1 = reps + (size_t)(rowBase + wr*64 + 32 + lc) * ND + hi*32;
  const u8* pb0 = reps + (size_t)(colBase + wc*64      + lc) * ND + hi*32;
  const u8* pb1 = reps + (size_t)(colBase + wc*64 + 32 + lc) * ND + hi*32;

  f32x16 acc00 = {}, acc01 = {}, acc10 = {}, acc11 = {};
  i32x8 a0E,a1E,b0E,b1E, a0O,a1O,b0O,b1O;

#define LDSET(S, off)                                                         \
  a0##S = ld32(pa0 + (off)); a1##S = ld32(pa1 + (off));                       \
  b0##S = ld32(pb0 + (off)); b1##S = ld32(pb1 + (off));
#define MM(S)                                                                 \
  acc00 = MFMA8(a0##S, b0##S, acc00);                                         \
  acc01 = MFMA8(a0##S, b1##S, acc01);                                         \
  acc10 = MFMA8(a1##S, b0##S, acc10);                                         \
  acc11 = MFMA8(a1##S, b1##S, acc11);

  // 8 k-chunks of 64 bytes; software-pipelined 1 deep (issue next, mfma cur).
  LDSET(E, 0);
  LDSET(O,  64); MM(E);
  LDSET(E, 128); MM(O);
  LDSET(O, 192); MM(E);
  LDSET(E, 256); MM(O);
  LDSET(O, 320); MM(E);
  LDSET(E, 384); MM(O);
  LDSET(O, 448); MM(E);
  MM(O);

  // Epilogue. 32x32 C layout: col = lane&31, row = (reg&3)+8*(reg>>2)+4*hi.
  // For fixed reg, one 32-lane half holds all 32 cols of one row: 5-step
  // shuffle-xor min within the half (xor<32 stays in-half).
  const float nc0 = norms[colBase + wc*64      + lc];
  const float nc1 = norms[colBase + wc*64 + 32 + lc];
  const int   c0g = colBase + wc*64      + lc;
  const int   c1g = colBase + wc*64 + 32 + lc;
  const float INF = __builtin_inff();

#define EPI(MI, ACCA, ACCB)                                                   \
  { _Pragma("unroll")                                                         \
    for (int reg = 0; reg < 16; ++reg) {                                      \
      const int r_g = rowBase + wr*64 + (MI)*32 + (reg&3) + 8*(reg>>2) + 4*hi;\
      const float ntr = norms[r_g];                                           \
      const float sq0 = ntr + nc0 - 2.0f * (ACCA)[reg];                       \
      const float sq1 = ntr + nc1 - 2.0f * (ACCB)[reg];                       \
      if (c0g == r_g + NB)   lpos1[r_g] = sq0;                                \
      if (c0g == r_g + 2*NB) lpos2[r_g] = sq0;                                \
      if (c1g == r_g + NB)   lpos1[r_g] = sq1;                                \
      if (c1g == r_g + 2*NB) lpos2[r_g] = sq1;                                \
      const bool e0 = (c0g == r_g) || (c0g == r_g+NB) || (c0g == r_g+2*NB);   \
      const bool e1 = (c1g == r_g) || (c1g == r_g+NB) || (c1g == r_g+2*NB);   \
      float vm = fminf(e0 ? INF : fmaxf(sq0, 0.0f),                           \
                       e1 ? INF : fmaxf(sq1, 0.0f));                          \
      _Pragma("unroll")                                                       \
      for (int off = 1; off < 32; off <<= 1)                                  \
        vm = fminf(vm, __shfl_xor(vm, off));                                  \
      if (lc == 0)                                                            \
        atomicMin(minsq + r_g, __float_as_uint(vm));                          \
    } }

  EPI(0, acc00, acc01);
  EPI(1, acc10, acc11);
}

__global__ __launch_bounds__(1024) void finalize(
    const float* __restrict__ lpos1, const float* __restrict__ lpos2,
    const float* __restrict__ dist12, const u32* __restrict__ minsq,
    float* __restrict__ out)
{
  __shared__ float red[16];
  const int tid = threadIdx.x;
  float s = 0.f;
  for (int r = tid; r < NB; r += 1024) {
    float l1 = sqrtf(fmaxf(lpos1[r], 0.f));
    float l2 = sqrtf(fmaxf(lpos2[r], 0.f));
    float neg = sqrtf(__uint_as_float(minsq[r]));   // already clamped >= 0
    float pos = l1 + l2 + dist12[r];
    s += fmaxf(pos - neg + 0.1f, 0.f) + fmaxf(l1, l2);
  }
  #pragma unroll
  for (int off = 32; off; off >>= 1) s += __shfl_down(s, off);
  if ((tid & 63) == 0) red[tid >> 6] = s;
  __syncthreads();
  if (tid == 0) {
    float t = 0.f;
    #pragma unroll
    for (int i = 0; i < 16; ++i) t += red[i];
    out[0] = t * (1.0f / NB);
  }
}

extern "C" void kernel_launch(void* const* d_in, const int* in_sizes, int n_in,
                              void* d_out, int out_size, void* d_ws, size_t ws_size,
                              hipStream_t stream) {
  const float* ts = (const float*)d_in[0];
  const float* i1 = (const float*)d_in[1];
  const float* i2 = (const float*)d_in[2];
  float* out = (float*)d_out;

  char* p = (char*)d_ws;
  u8* reps     = (u8*)p;             p += (size_t)NREPS * ND * sizeof(u8);   // 6.3 MB
  float* norms = (float*)p;          p += (size_t)NREPS * sizeof(float);
  float* dist12 = (float*)p;         p += (size_t)NB * sizeof(float);
  u32* minsq   = (u32*)p;            p += (size_t)NB * sizeof(u32);
  float* lpos1 = (float*)p;          p += (size_t)NB * sizeof(float);
  float* lpos2 = (float*)p;          p += (size_t)NB * sizeof(float);

  prep_all<<<NB, 256, 0, stream>>>(ts, i1, i2, reps, norms, dist12, minsq);
  dim3 grid(NB / BM, NREPS / BN);   // 32 x 48, M-fastest (L2 locality)
  gemm_min<<<grid, 512, 0, stream>>>(reps, norms, minsq, lpos1, lpos2);
  finalize<<<1, 1024, 0, stream>>>(lpos1, lpos2, dist12, minsq, out);
}

// Round 11
// 150.695 us; speedup vs baseline: 1.8424x; 1.8424x over previous
//
#include <hip/hip_runtime.h>
#include <hip/hip_bf16.h>

typedef unsigned short u16;
typedef unsigned int u32;
typedef __attribute__((ext_vector_type(8))) short bf16x8;
typedef __attribute__((ext_vector_type(4))) float f32x4;

#define NB 4096
#define ND 512
#define NREPS (3*NB)
#define BM 128
#define BN 256
#define BK 64
#define NKT (ND/BK)      // 8 K-tiles
#define ASZ (BM*BK)      // 16 KiB
#define BSZ (BN*BK)      // 32 KiB

// global -> LDS direct DMA, 16B/lane; LDS dest wave-uniform base + lane*16.
#define GLD16(gp, lp)                                                         \
  __builtin_amdgcn_global_load_lds(                                           \
      (const __attribute__((address_space(1))) void*)(gp),                    \
      (__attribute__((address_space(3))) void*)(lp), 16, 0, 0)

__device__ __forceinline__ u16 f2bf(float f) {
  union { float f; u32 u; } v; v.f = f;
  u32 u = v.u;
  u32 r = (u + 0x7FFFu + ((u >> 16) & 1u)) >> 16;  // round-to-nearest-even
  return (u16)r;
}

// Fused prep, no LDS/no barriers: waves 0..2 convert ts/i1/i2 row r -> bf16
// reps + fp32 norms; wave 3 re-reads i1/i2 (L2-hot) for dist12 + minsq init.
__global__ __launch_bounds__(256) void prep_all(
    const float* __restrict__ ts, const float* __restrict__ i1,
    const float* __restrict__ i2, u16* __restrict__ reps,
    float* __restrict__ norms, float* __restrict__ dist12,
    u32* __restrict__ minsq)
{
  const int r = blockIdx.x;
  const int tid = threadIdx.x;
  const int wave = tid >> 6, lane = tid & 63;

  if (wave < 3) {
    const float* src = (wave == 0) ? ts + (size_t)r * ND
                     : (wave == 1) ? i1 + (size_t)r * ND
                     :               i2 + (size_t)r * ND;
    const float4* s4 = (const float4*)src;
    float4 a = s4[lane*2+0];
    float4 b = s4[lane*2+1];
    float ss = a.x*a.x + a.y*a.y + a.z*a.z + a.w*a.w
             + b.x*b.x + b.y*b.y + b.z*b.z + b.w*b.w;
    uint4 pk;
    pk.x = (u32)f2bf(a.x) | ((u32)f2bf(a.y) << 16);
    pk.y = (u32)f2bf(a.z) | ((u32)f2bf(a.w) << 16);
    pk.z = (u32)f2bf(b.x) | ((u32)f2bf(b.y) << 16);
    pk.w = (u32)f2bf(b.z) | ((u32)f2bf(b.w) << 16);
    *(uint4*)(reps + (size_t)(wave*NB + r) * ND + lane*8) = pk;
    #pragma unroll
    for (int off = 32; off; off >>= 1) ss += __shfl_down(ss, off);
    if (lane == 0) norms[wave*NB + r] = ss;
  } else {
    const float4* a4 = (const float4*)(i1 + (size_t)r * ND);
    const float4* b4 = (const float4*)(i2 + (size_t)r * ND);
    float ss = 0.f;
    #pragma unroll
    for (int i = 0; i < 2; ++i) {
      float4 a = a4[lane*2+i], b = b4[lane*2+i];
      float d0 = a.x - b.x + 1e-6f, d1 = a.y - b.y + 1e-6f;
      float d2 = a.z - b.z + 1e-6f, d3 = a.w - b.w + 1e-6f;
      ss += d0*d0 + d1*d1 + d2*d2 + d3*d3;
    }
    #pragma unroll
    for (int off = 32; off; off >>= 1) ss += __shfl_down(ss, off);
    if (lane == 0) { dist12[r] = sqrtf(ss); minsq[r] = 0x7F800000u; }
  }
}

// Fused distance-GEMM + per-row min + diagonal picks, with ts@ts^T SYMMETRY:
// ts-region tiles (colBase < NB) are kept only when 2*ny <= mx (lower
// triangle in tile space, 272/512 tiles); kept ts tiles update BOTH
// minsq[row] (min over cols) and minsq[col] (min over rows). min is
// idempotent -> overlapping coverage harmless; exclusion c==r symmetric.
// Structure otherwise = R7 (best measured): 128x256 tile, BK=64, 8 waves
// (2Mx4N), single-buffer 48 KiB LDS, stage->sync->compute->sync.
// Grid dim3(32,48) M-fastest; skipped blocks exit before any barrier.
__global__ __launch_bounds__(512) void gemm_min(
    const u16* __restrict__ reps, const float* __restrict__ norms,
    u32* __restrict__ minsq, float* __restrict__ lpos1,
    float* __restrict__ lpos2)
{
  const int mx = blockIdx.x, ny = blockIdx.y;
  const int rowBase = mx * BM;     // ts rows
  const int colBase = ny * BN;     // reps rows (output cols)
  const bool tsTile = (colBase < NB);
  if (tsTile && 2*ny > mx) return;             // symmetric skip (uniform)

  __shared__ u16 As[ASZ];
  __shared__ u16 Bs[BSZ];
  const int tid  = threadIdx.x;
  const int lane = tid & 63;
  const int wave = tid >> 6;          // 0..7
  const int wr = wave >> 2;           // 0..1 (M half)
  const int wc = wave & 3;            // 0..3 (N quarter)
  const int fr = lane & 15, fg = lane >> 4;

  // Staging: rows are 128 B (8 granules of 16 B); one GLD16 covers 8 rows.
  // A = 16 chunks (2/wave), B = 32 chunks (4/wave). Src granule XOR-swizzled.
  const int rloc = lane >> 3;
  const int sp   = lane & 7;
  const u16* srcA[2]; u16* dstA[2];
  const u16* srcB[4]; u16* dstB[4];
  #pragma unroll
  for (int i = 0; i < 2; ++i) {
    const int r = wave*16 + i*8 + rloc;
    const int g = sp ^ (r & 7);
    srcA[i] = reps + (size_t)(rowBase + r) * ND + g*8;
    dstA[i] = &As[(wave*16 + i*8) * BK];
  }
  #pragma unroll
  for (int i = 0; i < 4; ++i) {
    const int r = wave*32 + i*8 + rloc;
    const int g = sp ^ (r & 7);
    srcB[i] = reps + (size_t)(colBase + r) * ND + g*8;
    dstB[i] = &Bs[(wave*32 + i*8) * BK];
  }

  f32x4 acc[4][4];
  const f32x4 zero = {0.f, 0.f, 0.f, 0.f};
  #pragma unroll
  for (int i = 0; i < 4; ++i)
    #pragma unroll
    for (int j = 0; j < 4; ++j)
      acc[i][j] = zero;

  for (int kt = 0; kt < NKT; ++kt) {
    const int koff = kt * BK;
    #pragma unroll
    for (int i = 0; i < 2; ++i) GLD16(srcA[i] + koff, dstA[i]);
    #pragma unroll
    for (int i = 0; i < 4; ++i) GLD16(srcB[i] + koff, dstB[i]);
    __syncthreads();

    bf16x8 af[4][2], bfr[4][2];
    #pragma unroll
    for (int mf = 0; mf < 4; ++mf)
      #pragma unroll
      for (int ks = 0; ks < 2; ++ks) {
        const int rowA = wr*64 + mf*16 + fr;
        const int slot = ks*4 + fg;
        af[mf][ks]  = *(const bf16x8*)&As[rowA*BK + (slot ^ (rowA & 7))*8];
        const int rowB = wc*64 + mf*16 + fr;
        bfr[mf][ks] = *(const bf16x8*)&Bs[rowB*BK + (slot ^ (rowB & 7))*8];
      }
    #pragma unroll
    for (int ks = 0; ks < 2; ++ks)
      #pragma unroll
      for (int mf = 0; mf < 4; ++mf)
        #pragma unroll
        for (int nf = 0; nf < 4; ++nf)
          acc[mf][nf] = __builtin_amdgcn_mfma_f32_16x16x32_bf16(
              af[mf][ks], bfr[nf][ks], acc[mf][nf], 0, 0, 0);
    __syncthreads();
  }

  // Epilogue. C layout: col = fr, row = fg*4 + q within each 16x16 frag.
  // Row-min (all tiles) + col-min (ts tiles only, = transpose fold).
  float ncol[4];
  #pragma unroll
  for (int nf = 0; nf < 4; ++nf)
    ncol[nf] = norms[colBase + wc*64 + nf*16 + fr];
  const float INF = __builtin_inff();
  float cmin[4] = {INF, INF, INF, INF};

  #pragma unroll
  for (int mf = 0; mf < 4; ++mf) {
    #pragma unroll
    for (int q = 0; q < 4; ++q) {
      const int r_g = rowBase + wr*64 + mf*16 + fg*4 + q;
      const float ntr = norms[r_g];
      float vm = INF;
      #pragma unroll
      for (int nf = 0; nf < 4; ++nf) {
        const int c_g = colBase + wc*64 + nf*16 + fr;
        const float dot = acc[mf][nf][q];
        const float sq = ntr + ncol[nf] - 2.0f * dot;
        if (c_g == r_g + NB)   lpos1[r_g] = sq;   // unique writer
        if (c_g == r_g + 2*NB) lpos2[r_g] = sq;   // unique writer
        const bool excl = (c_g == r_g) || (c_g == r_g + NB) || (c_g == r_g + 2*NB);
        const float v = excl ? INF : fmaxf(sq, 0.0f);
        vm = fminf(vm, v);
        cmin[nf] = fminf(cmin[nf], v);
      }
      #pragma unroll
      for (int off = 1; off < 16; off <<= 1)
        vm = fminf(vm, __shfl_xor(vm, off));
      if (fr == 0)
        atomicMin(minsq + r_g, __float_as_uint(vm));  // nonneg floats as uints
    }
  }

  if (tsTile) {
    // Fold transposes: min over this tile's 128 rows for each of our 4 cols.
    #pragma unroll
    for (int nf = 0; nf < 4; ++nf) {
      float cm = cmin[nf];
      cm = fminf(cm, __shfl_xor(cm, 16));   // reduce across fg groups
      cm = fminf(cm, __shfl_xor(cm, 32));
      if (fg == 0) {
        const int c_g = colBase + wc*64 + nf*16 + fr;
        atomicMin(minsq + c_g, __float_as_uint(cm));
      }
    }
  }
}

__global__ __launch_bounds__(1024) void finalize(
    const float* __restrict__ lpos1, const float* __restrict__ lpos2,
    const float* __restrict__ dist12, const u32* __restrict__ minsq,
    float* __restrict__ out)
{
  __shared__ float red[16];
  const int tid = threadIdx.x;
  float s = 0.f;
  for (int r = tid; r < NB; r += 1024) {
    float l1 = sqrtf(fmaxf(lpos1[r], 0.f));
    float l2 = sqrtf(fmaxf(lpos2[r], 0.f));
    float neg = sqrtf(__uint_as_float(minsq[r]));   // already clamped >= 0
    float pos = l1 + l2 + dist12[r];
    s += fmaxf(pos - neg + 0.1f, 0.f) + fmaxf(l1, l2);
  }
  #pragma unroll
  for (int off = 32; off; off >>= 1) s += __shfl_down(s, off);
  if ((tid & 63) == 0) red[tid >> 6] = s;
  __syncthreads();
  if (tid == 0) {
    float t = 0.f;
    #pragma unroll
    for (int i = 0; i < 16; ++i) t += red[i];
    out[0] = t * (1.0f / NB);
  }
}

extern "C" void kernel_launch(void* const* d_in, const int* in_sizes, int n_in,
                              void* d_out, int out_size, void* d_ws, size_t ws_size,
                              hipStream_t stream) {
  const float* ts = (const float*)d_in[0];
  const float* i1 = (const float*)d_in[1];
  const float* i2 = (const float*)d_in[2];
  float* out = (float*)d_out;

  char* p = (char*)d_ws;
  u16* reps    = (u16*)p;            p += (size_t)NREPS * ND * sizeof(u16);  // 12.6 MB
  float* norms = (float*)p;          p += (size_t)NREPS * sizeof(float);
  float* dist12 = (float*)p;         p += (size_t)NB * sizeof(float);
  u32* minsq   = (u32*)p;            p += (size_t)NB * sizeof(u32);
  float* lpos1 = (float*)p;          p += (size_t)NB * sizeof(float);
  float* lpos2 = (float*)p;          p += (size_t)NB * sizeof(float);

  prep_all<<<NB, 256, 0, stream>>>(ts, i1, i2, reps, norms, dist12, minsq);
  dim3 grid(NB / BM, NREPS / BN);   // 32 x 48, M-fastest (L2 locality)
  gemm_min<<<grid, 512, 0, stream>>>(reps, norms, minsq, lpos1, lpos2);
  finalize<<<1, 1024, 0, stream>>>(lpos1, lpos2, dist12, minsq, out);
}

// Round 13
// 134.913 us; speedup vs baseline: 2.0579x; 1.1170x over previous
//
#include <hip/hip_runtime.h>
#include <hip/hip_bf16.h>
#include <hip/hip_fp8.h>

typedef unsigned char u8;
typedef unsigned int u32;
typedef long long i64;
typedef __attribute__((ext_vector_type(4))) float f32x4;

#define NB 4096
#define ND 512          // bytes per fp8 row
#define NREPS (3*NB)
#define BM 128
#define BN 256
#define BK 128          // fp8 bytes per K-step -> NKT=4
#define NKT (ND/BK)
#define ASZ (BM*BK)     // 16 KiB
#define BSZ (BN*BK)     // 32 KiB

// global -> LDS direct DMA, 16B/lane; LDS dest wave-uniform base + lane*16.
#define GLD16(gp, lp)                                                         \
  __builtin_amdgcn_global_load_lds(                                           \
      (const __attribute__((address_space(1))) void*)(gp),                    \
      (__attribute__((address_space(3))) void*)(lp), 16, 0, 0)

__device__ __forceinline__ u32 pk4(float a, float b, float c, float d) {
  __hip_fp8_e4m3 qa(a), qb(b), qc(c), qd(d);
  return (u32)qa.__x | ((u32)qb.__x << 8) | ((u32)qc.__x << 16) | ((u32)qd.__x << 24);
}

// Fused prep, no LDS/no barriers: waves 0..2 convert ts/i1/i2 row r -> fp8
// reps + fp32 norms (norms from ORIGINAL fp32); wave 3 re-reads i1/i2
// (L2-hot) for dist12 + minsq init. Block 0 also zeroes out[0] for the
// atomicAdd finalize (stream order guarantees it lands before finalize).
__global__ __launch_bounds__(256) void prep_all(
    const float* __restrict__ ts, const float* __restrict__ i1,
    const float* __restrict__ i2, u8* __restrict__ reps,
    float* __restrict__ norms, float* __restrict__ dist12,
    u32* __restrict__ minsq, float* __restrict__ out)
{
  const int r = blockIdx.x;
  const int tid = threadIdx.x;
  const int wave = tid >> 6, lane = tid & 63;
  if (r == 0 && tid == 0) out[0] = 0.f;

  if (wave < 3) {
    const float* src = (wave == 0) ? ts + (size_t)r * ND
                     : (wave == 1) ? i1 + (size_t)r * ND
                     :               i2 + (size_t)r * ND;
    const float4* s4 = (const float4*)src;
    float4 a = s4[lane*2+0];
    float4 b = s4[lane*2+1];
    float ss = a.x*a.x + a.y*a.y + a.z*a.z + a.w*a.w
             + b.x*b.x + b.y*b.y + b.z*b.z + b.w*b.w;
    uint2 pk;
    pk.x = pk4(a.x, a.y, a.z, a.w);
    pk.y = pk4(b.x, b.y, b.z, b.w);
    *(uint2*)(reps + (size_t)(wave*NB + r) * ND + lane*8) = pk;
    #pragma unroll
    for (int off = 32; off; off >>= 1) ss += __shfl_down(ss, off);
    if (lane == 0) norms[wave*NB + r] = ss;
  } else {
    const float4* a4 = (const float4*)(i1 + (size_t)r * ND);
    const float4* b4 = (const float4*)(i2 + (size_t)r * ND);
    float ss = 0.f;
    #pragma unroll
    for (int i = 0; i < 2; ++i) {
      float4 a = a4[lane*2+i], b = b4[lane*2+i];
      float d0 = a.x - b.x + 1e-6f, d1 = a.y - b.y + 1e-6f;
      float d2 = a.z - b.z + 1e-6f, d3 = a.w - b.w + 1e-6f;
      ss += d0*d0 + d1*d1 + d2*d2 + d3*d3;
    }
    #pragma unroll
    for (int off = 32; off; off >>= 1) ss += __shfl_down(ss, off);
    if (lane == 0) { dist12[r] = sqrtf(ss); minsq[r] = 0x7F800000u; }
  }
}

// fp8 16x16x32 operand read: lane (fr=row, fg) needs k-bytes s*32 + fg*8..+7
// = logical granule q = 2s + (fg>>1), byte (fg&1)*8. Physical slot = q ^
// (row&7) (matches the staging-side source swizzle). b64 read; bank spread
// >= 2-way-free for all 64 lanes (row stride 128 B = 32 banks -> only the
// granule XOR distributes, 8 granules x 2 lanes each, disjoint byte-halves).
__device__ __forceinline__ i64 rd8(const u8* __restrict__ S, int row,
                                   int s, int f) {
  const int q = (2*s + (f >> 1)) ^ (row & 7);
  return *(const i64*)&S[row*BK + q*16 + (f & 1)*8];
}

#define MFMA16(a,b,c) __builtin_amdgcn_mfma_f32_16x16x32_fp8_fp8((a),(b),(c),0,0,0)

// Fused distance-GEMM (fp8 e4m3) + per-row min + diagonal picks + ts@ts^T
// symmetry (R11). 128x256 tile, BK=128 -> NKT=4 (half the vmcnt(0) drains),
// staged bytes halved vs bf16 (192 KB/tile), LDS 48 KiB, 8 waves (2Mx4N),
// wave-tile 64x64 = 4x4 frags of 16x16, MFMA count identical to bf16 path.
// Grid dim3(32,48) M-fastest; ts tiles kept iff 2*ny <= mx, kept ts tiles
// fold the transpose into minsq[col] (min idempotent).
__global__ __launch_bounds__(512) void gemm_min(
    const u8* __restrict__ reps, const float* __restrict__ norms,
    u32* __restrict__ minsq, float* __restrict__ lpos1,
    float* __restrict__ lpos2)
{
  const int mx = blockIdx.x, ny = blockIdx.y;
  const int rowBase = mx * BM;     // ts rows
  const int colBase = ny * BN;     // reps rows (output cols)
  const bool tsTile = (colBase < NB);
  if (tsTile && 2*ny > mx) return;             // symmetric skip (uniform)

  __shared__ u8 As[ASZ];
  __shared__ u8 Bs[BSZ];
  const int tid  = threadIdx.x;
  const int lane = tid & 63;
  const int wave = tid >> 6;          // 0..7
  const int wr = wave >> 2;           // 0..1 (M half)
  const int wc = wave & 3;            // 0..3 (N quarter)
  const int fr = lane & 15, fg = lane >> 4;

  // Staging: rows are 128 B (8 granules of 16 B); one GLD16 covers 8 rows.
  // A = 16 chunks (2/wave), B = 32 chunks (4/wave). Src granule XOR-swizzled.
  const int rloc = lane >> 3;          // row within 8-row chunk (== r&7)
  const int sp   = lane & 7;           // physical granule slot
  const int g    = sp ^ rloc;          // swizzled source granule
  const u8* srcA[2]; u8* dstA[2];
  const u8* srcB[4]; u8* dstB[4];
  #pragma unroll
  for (int i = 0; i < 2; ++i) {
    const int r = wave*16 + i*8 + rloc;
    srcA[i] = reps + (size_t)(rowBase + r) * ND + g*16;
    dstA[i] = &As[(wave*16 + i*8) * BK];
  }
  #pragma unroll
  for (int i = 0; i < 4; ++i) {
    const int r = wave*32 + i*8 + rloc;
    srcB[i] = reps + (size_t)(colBase + r) * ND + g*16;
    dstB[i] = &Bs[(wave*32 + i*8) * BK];
  }

  f32x4 acc[4][4];
  const f32x4 zero = {0.f, 0.f, 0.f, 0.f};
  #pragma unroll
  for (int i = 0; i < 4; ++i)
    #pragma unroll
    for (int j = 0; j < 4; ++j)
      acc[i][j] = zero;

  for (int kt = 0; kt < NKT; ++kt) {
    const int koff = kt * BK;
    #pragma unroll
    for (int i = 0; i < 2; ++i) GLD16(srcA[i] + koff, dstA[i]);
    #pragma unroll
    for (int i = 0; i < 4; ++i) GLD16(srcB[i] + koff, dstB[i]);
    __syncthreads();

    i64 af[4][4], bfr[4][4];            // [frag][k-slice] - all const-indexed
    #pragma unroll
    for (int mf = 0; mf < 4; ++mf)
      #pragma unroll
      for (int s = 0; s < 4; ++s) {
        af[mf][s]  = rd8(As, wr*64 + mf*16 + fr, s, fg);
        bfr[mf][s] = rd8(Bs, wc*64 + mf*16 + fr, s, fg);
      }
    #pragma unroll
    for (int s = 0; s < 4; ++s)
      #pragma unroll
      for (int mf = 0; mf < 4; ++mf)
        #pragma unroll
        for (int nf = 0; nf < 4; ++nf)
          acc[mf][nf] = MFMA16(af[mf][s], bfr[nf][s], acc[mf][nf]);
    __syncthreads();
  }

  // Epilogue. C layout: col = fr, row = fg*4 + q within each 16x16 frag.
  // Row-min (all tiles) + col-min fold (ts tiles only).
  float ncol[4];
  #pragma unroll
  for (int nf = 0; nf < 4; ++nf)
    ncol[nf] = norms[colBase + wc*64 + nf*16 + fr];
  const float INF = __builtin_inff();
  float cmin[4] = {INF, INF, INF, INF};

  #pragma unroll
  for (int mf = 0; mf < 4; ++mf) {
    #pragma unroll
    for (int q = 0; q < 4; ++q) {
      const int r_g = rowBase + wr*64 + mf*16 + fg*4 + q;
      const float ntr = norms[r_g];
      float vm = INF;
      #pragma unroll
      for (int nf = 0; nf < 4; ++nf) {
        const int c_g = colBase + wc*64 + nf*16 + fr;
        const float dot = acc[mf][nf][q];
        const float sq = ntr + ncol[nf] - 2.0f * dot;
        if (c_g == r_g + NB)   lpos1[r_g] = sq;   // unique writer
        if (c_g == r_g + 2*NB) lpos2[r_g] = sq;   // unique writer
        const bool excl = (c_g == r_g) || (c_g == r_g + NB) || (c_g == r_g + 2*NB);
        const float v = excl ? INF : fmaxf(sq, 0.0f);
        vm = fminf(vm, v);
        cmin[nf] = fminf(cmin[nf], v);
      }
      #pragma unroll
      for (int off = 1; off < 16; off <<= 1)
        vm = fminf(vm, __shfl_xor(vm, off));
      if (fr == 0)
        atomicMin(minsq + r_g, __float_as_uint(vm));  // nonneg floats as uints
    }
  }

  if (tsTile) {
    #pragma unroll
    for (int nf = 0; nf < 4; ++nf) {
      float cm = cmin[nf];
      cm = fminf(cm, __shfl_xor(cm, 16));
      cm = fminf(cm, __shfl_xor(cm, 32));
      if (fg == 0) {
        const int c_g = colBase + wc*64 + nf*16 + fr;
        atomicMin(minsq + c_g, __float_as_uint(cm));
      }
    }
  }
}

// Multi-block finalize: 16 blocks x 256 threads, one row per thread,
// per-block reduce + one atomicAdd (out zeroed by prep_all).
__global__ __launch_bounds__(256) void finalize(
    const float* __restrict__ lpos1, const float* __restrict__ lpos2,
    const float* __restrict__ dist12, const u32* __restrict__ minsq,
    float* __restrict__ out)
{
  __shared__ float red[4];
  const int tid = threadIdx.x;
  const int r = blockIdx.x * 256 + tid;
  float l1 = sqrtf(fmaxf(lpos1[r], 0.f));
  float l2 = sqrtf(fmaxf(lpos2[r], 0.f));
  float neg = sqrtf(__uint_as_float(minsq[r]));   // already clamped >= 0
  float pos = l1 + l2 + dist12[r];
  float s = fmaxf(pos - neg + 0.1f, 0.f) + fmaxf(l1, l2);
  #pragma unroll
  for (int off = 32; off; off >>= 1) s += __shfl_down(s, off);
  if ((tid & 63) == 0) red[tid >> 6] = s;
  __syncthreads();
  if (tid == 0)
    atomicAdd(out, (red[0] + red[1] + red[2] + red[3]) * (1.0f / NB));
}

extern "C" void kernel_launch(void* const* d_in, const int* in_sizes, int n_in,
                              void* d_out, int out_size, void* d_ws, size_t ws_size,
                              hipStream_t stream) {
  const float* ts = (const float*)d_in[0];
  const float* i1 = (const float*)d_in[1];
  const float* i2 = (const float*)d_in[2];
  float* out = (float*)d_out;

  char* p = (char*)d_ws;
  u8* reps     = (u8*)p;             p += (size_t)NREPS * ND * sizeof(u8);   // 6.3 MB
  float* norms = (float*)p;          p += (size_t)NREPS * sizeof(float);
  float* dist12 = (float*)p;         p += (size_t)NB * sizeof(float);
  u32* minsq   = (u32*)p;            p += (size_t)NB * sizeof(u32);
  float* lpos1 = (float*)p;          p += (size_t)NB * sizeof(float);
  float* lpos2 = (float*)p;          p += (size_t)NB * sizeof(float);

  prep_all<<<NB, 256, 0, stream>>>(ts, i1, i2, reps, norms, dist12, minsq, out);
  dim3 grid(NB / BM, NREPS / BN);   // 32 x 48, M-fastest (L2 locality)
  gemm_min<<<grid, 512, 0, stream>>>(reps, norms, minsq, lpos1, lpos2);
  finalize<<<16, 256, 0, stream>>>(lpos1, lpos2, dist12, minsq, out);
}